// Round 7
// baseline (279.173 us; speedup 1.0000x reference)
//
#include <hip/hip_runtime.h>
#include <hip/hip_bf16.h>

typedef __attribute__((ext_vector_type(8))) short bf16x8;
typedef __attribute__((ext_vector_type(4))) short bf16x4;
typedef __attribute__((ext_vector_type(4))) float f32x4;
typedef __attribute__((ext_vector_type(16))) float f32x16;
typedef __attribute__((ext_vector_type(4))) unsigned int uint4v;

__device__ __forceinline__ short f2bf(float f) {
    unsigned int u = __float_as_uint(f);
    u += 0x7FFFu + ((u >> 16) & 1u);   // round-to-nearest-even
    return (short)(u >> 16);
}

__device__ __forceinline__ unsigned cvtpk(float lo, float hi) {
    unsigned r;
    asm("v_cvt_pk_bf16_f32 %0, %1, %2" : "=v"(r) : "v"(lo), "v"(hi));
    return r;
}

// async global -> LDS, 16 B per lane; LDS dest = wave-uniform base + lane*16
__device__ __forceinline__ void gload_lds16(const void* g, void* l) {
    __builtin_amdgcn_global_load_lds(
        (const __attribute__((address_space(1))) void*)g,
        (__attribute__((address_space(3))) void*)l, 16, 0, 0);
}

// ---------------- cast x (f32) -> bf16 ----------------
__global__ __launch_bounds__(256) void cast_kernel(const float* __restrict__ in,
                                                   short* __restrict__ out, int n4) {
    int i = blockIdx.x * 256 + threadIdx.x;
    if (i >= n4) return;
    const f32x4 v = *(const f32x4*)(in + (size_t)i * 4);
    bf16x4 o;
    o[0] = f2bf(v[0]); o[1] = f2bf(v[1]); o[2] = f2bf(v[2]); o[3] = f2bf(v[3]);
    *(bf16x4*)(out + (size_t)i * 4) = o;
}

// ---------------- transpose + cast W [R][C] f32 -> WT [C][R] bf16 ----------------
__global__ __launch_bounds__(256) void transpose_cast_kernel(const float* __restrict__ W,
                                                             short* __restrict__ WT,
                                                             int R, int C) {
    __shared__ float tile[64][65];
    const int bc = blockIdx.x * 64;
    const int br = blockIdx.y * 64;
    const int t = threadIdx.x;
#pragma unroll
    for (int i = 0; i < 16; ++i) {
        int o = t + 256 * i;
        int r = o >> 6, c = o & 63;
        tile[r][c] = W[(size_t)(br + r) * C + bc + c];
    }
    __syncthreads();
#pragma unroll
    for (int i = 0; i < 16; ++i) {
        int o = t + 256 * i;
        int c = o >> 6, r = o & 63;
        WT[(size_t)(bc + c) * R + br + r] = f2bf(tile[r][c]);
    }
}

// ---------------- GEMM1: xb[16384][768] @ WqkvT[2304][768]^T + b ->
//   Qh[64][2048][96] (pre-scaled by 1/sqrt(768)*log2(e)),
//   Kh[64][2048][104] (row-padded), Vt[64][32][96][64] (V^T, chunk-XOR-swizzled)
//   2-phase pipelined: dbuf LDS, stage(t+1) issued BEFORE compute(t), 1 barrier/iter ----
__global__ __launch_bounds__(256, 2) void gemm1_kernel(
    const short* __restrict__ A, const short* __restrict__ BT,
    const float* __restrict__ bias,
    short* __restrict__ Qh, short* __restrict__ Kh, short* __restrict__ Vt)
{
    __shared__ short As[2][128][64];
    __shared__ short Bs[2][128][64];
    const int K = 768;
    const int t = threadIdx.x;
    const int w = t >> 6, l = t & 63;
    const int wr = w >> 1, wc = w & 1;
    const int lr = l & 15, lg = l >> 4;

    const int srow = w * 32 + (l >> 3);
    const int scol = (l & 7) * 8;
    const short* Ag = A + (size_t)blockIdx.x * 128 * K + (size_t)srow * K + scol;
    const short* Bg = BT + (size_t)blockIdx.y * 128 * K + (size_t)srow * K + scol;

    const f32x4 z4 = {0.f, 0.f, 0.f, 0.f};
    f32x4 acc[4][4];
#pragma unroll
    for (int i = 0; i < 4; ++i)
#pragma unroll
        for (int j = 0; j < 4; ++j) acc[i][j] = z4;

    auto stage = [&](int kt, int buf) {
#pragma unroll
        for (int i = 0; i < 4; ++i) {
            gload_lds16(Ag + kt * 64 + (size_t)(i * 8) * K, &As[buf][w * 32 + i * 8][0]);
            gload_lds16(Bg + kt * 64 + (size_t)(i * 8) * K, &Bs[buf][w * 32 + i * 8][0]);
        }
    };
    auto compute = [&](int buf) {
#pragma unroll
        for (int kk = 0; kk < 2; ++kk) {
            bf16x8 af[4], bfr[4];
#pragma unroll
            for (int mi = 0; mi < 4; ++mi)
                af[mi] = *(const bf16x8*)&As[buf][wr * 64 + mi * 16 + lr][kk * 32 + lg * 8];
#pragma unroll
            for (int ni = 0; ni < 4; ++ni)
                bfr[ni] = *(const bf16x8*)&Bs[buf][wc * 64 + ni * 16 + lr][kk * 32 + lg * 8];
#pragma unroll
            for (int mi = 0; mi < 4; ++mi)
#pragma unroll
                for (int ni = 0; ni < 4; ++ni)
                    acc[mi][ni] = __builtin_amdgcn_mfma_f32_16x16x32_bf16(
                        af[mi], bfr[ni], acc[mi][ni], 0, 0, 0);
        }
    };

    stage(0, 0);
    __syncthreads();                  // vmcnt(0): buf0 ready
    for (int kt = 0; kt < 12; kt += 2) {
        stage(kt + 1, 1);             // async; drains at the next barrier
        compute(0);
        __syncthreads();              // buf1 ready; buf0 free
        if (kt + 2 < 12) stage(kt + 2, 0);
        compute(1);
        __syncthreads();              // buf0 ready; buf1 free
    }

    const float qs = 0.05205877f; // (1/sqrt(768)) * log2(e), folded into Q
    const int rb = blockIdx.x * 128 + wr * 64;
    const int cb = blockIdx.y * 128 + wc * 64;
#pragma unroll
    for (int ni = 0; ni < 4; ++ni) {
        const int c = cb + ni * 16 + lr;
        const float bv = bias[c];
        const int which = (c >= 1536) ? 2 : (c >= 768 ? 1 : 0);
        const int cc = c - which * 768;
        const int h = cc / 96;
        const int d = cc - h * 96;
#pragma unroll
        for (int mi = 0; mi < 4; ++mi) {
            const int r0 = rb + mi * 16 + lg * 4;
            const int b = r0 >> 11, n0 = r0 & 2047;
            const int hb = b * 8 + h;
            if (which == 2) {
                bf16x4 pk;
#pragma unroll
                for (int r = 0; r < 4; ++r) pk[r] = f2bf(acc[mi][ni][r] + bv);
                // V^T tiled + swizzled: tile = n0>>6, chunk c0 = (n0&63)>>3 stored at c0^(d&7)
                const int ktile = n0 >> 6;
                const int s = (((n0 & 63) >> 3) ^ (d & 7));
                *(bf16x4*)&Vt[((size_t)(hb * 32 + ktile) * 96 + d) * 64 + s * 8 + (n0 & 7)] = pk;
            } else if (which == 1) {
#pragma unroll
                for (int r = 0; r < 4; ++r)
                    Kh[((size_t)hb * 2048 + n0 + r) * 104 + d] = f2bf(acc[mi][ni][r] + bv);
            } else {
#pragma unroll
                for (int r = 0; r < 4; ++r)
                    Qh[((size_t)hb * 2048 + n0 + r) * 96 + d] = f2bf((acc[mi][ni][r] + bv) * qs);
            }
        }
    }
}

// ---------------- attention: QBLK=128 (4 waves x 32 q-rows), KVBLK=64 (two 32-kv halves),
//   32x32x16 MFMA, double-buffered K/V via global_load_lds, in-register P. (unchanged R6) ----
__global__ __launch_bounds__(256, 3) void attn_kernel(
    const short* __restrict__ Qh, const short* __restrict__ Kh,
    const short* __restrict__ Vt, short* __restrict__ AO)
{
    // K0 0..13311 | K1 13312..26623 | V0 26624..38911 | V1 38912..51199
    __shared__ __align__(16) char smem[51200];
    short (*K0)[104] = (short (*)[104])smem;
    short (*K1)[104] = (short (*)[104])(smem + 13312);
    short* V0 = (short*)(smem + 26624);
    short* V1 = (short*)(smem + 38912);
    short (*Qs)[96] = (short (*)[96])smem;
    float (*ltab)[32] = (float (*)[32])smem;

    const int t = threadIdx.x;
    const int w = t >> 6, l = t & 63;
    const int ql = l & 31, hi = l >> 5;

    const unsigned L = blockIdx.y * 16 + blockIdx.x;
    const int bh = (int)((L & 7) + 8 * (L >> 7));
    const int qt = (int)((L >> 3) & 15);

    const short* Qg  = Qh + ((size_t)bh * 2048 + (size_t)qt * 128) * 96;
    const short* Kgp = Kh + (size_t)bh * 2048 * 104;
    const short* Vgt = Vt + (size_t)bh * 32 * 6144;

#pragma unroll
    for (int j = 0; j < 6; ++j) {
        const int idx = j * 4 + w;
        gload_lds16(Qg + idx * 512 + l * 8, smem + idx * 1024);
    }
    __syncthreads();
    bf16x8 qf[6];
#pragma unroll
    for (int kk = 0; kk < 6; ++kk)
        qf[kk] = *(const bf16x8*)&Qs[w * 32 + ql][kk * 16 + hi * 8];
    __syncthreads();

    auto stageK = [&](int kt, short (*wK)[104]) {
        const short* s = Kgp + kt * 6656 + l * 8;
#pragma unroll
        for (int j = 0; j < 4; ++j) {
            const int idx = j * 4 + w;
            if (idx < 13) gload_lds16(s + idx * 512, (char*)wK + idx * 1024);
        }
    };
    auto stageV = [&](int kt, short* wV) {
        const short* s = Vgt + kt * 6144 + l * 8;
#pragma unroll
        for (int j = 0; j < 3; ++j) {
            const int idx = j * 4 + w;
            gload_lds16(s + idx * 512, (char*)wV + idx * 1024);
        }
    };

    stageK(0, K0);
    stageV(0, V0);
    __syncthreads();

    f32x16 oacc[3];
#pragma unroll
    for (int i = 0; i < 3; ++i)
#pragma unroll
        for (int r = 0; r < 16; ++r) oacc[i][r] = 0.f;
    float lacc = 0.f;

    auto iter = [&](int kt, short (*rK)[104], const short* rV,
                    short (*wK)[104], short* wV) {
        if (kt < 31) { stageK(kt + 1, wK); stageV(kt + 1, wV); }

#pragma unroll
        for (int h = 0; h < 2; ++h) {
            f32x16 sa;
#pragma unroll
            for (int r = 0; r < 16; ++r) sa[r] = 0.f;
            __builtin_amdgcn_s_setprio(1);
#pragma unroll
            for (int kk = 0; kk < 6; ++kk) {
                bf16x8 kf = *(const bf16x8*)&rK[h * 32 + ql][kk * 16 + hi * 8];
                sa = __builtin_amdgcn_mfma_f32_32x32x16_bf16(kf, qf[kk], sa, 0, 0, 0);
            }
            __builtin_amdgcn_s_setprio(0);

            float p[16];
#pragma unroll
            for (int r = 0; r < 16; ++r) {
                p[r] = __builtin_amdgcn_exp2f(sa[r]);
                lacc += p[r];
            }
            unsigned x0 = cvtpk(p[0], p[1]),   y0 = cvtpk(p[4], p[5]);
            unsigned x1 = cvtpk(p[2], p[3]),   y1 = cvtpk(p[6], p[7]);
            unsigned x2 = cvtpk(p[8], p[9]),   y2 = cvtpk(p[12], p[13]);
            unsigned x3 = cvtpk(p[10], p[11]), y3 = cvtpk(p[14], p[15]);
            asm("v_permlane32_swap_b32 %0, %1" : "+v"(x0), "+v"(y0));
            asm("v_permlane32_swap_b32 %0, %1" : "+v"(x1), "+v"(y1));
            asm("v_permlane32_swap_b32 %0, %1" : "+v"(x2), "+v"(y2));
            asm("v_permlane32_swap_b32 %0, %1" : "+v"(x3), "+v"(y3));
            uint4v uA; uA[0] = x0; uA[1] = x1; uA[2] = y0; uA[3] = y1;
            uint4v uB; uB[0] = x2; uB[1] = x3; uB[2] = y2; uB[3] = y3;
            bf16x8 pa0 = __builtin_bit_cast(bf16x8, uA);
            bf16x8 pa1 = __builtin_bit_cast(bf16x8, uB);

            __builtin_amdgcn_s_setprio(1);
#pragma unroll
            for (int kb = 0; kb < 2; ++kb) {
                const int c = (h * 2 + kb) * 2 + hi;
                const bf16x8 paf = kb ? pa1 : pa0;
#pragma unroll
                for (int db = 0; db < 3; ++db) {
                    const int row = db * 32 + ql;
                    bf16x8 vf = *(const bf16x8*)&rV[row * 64 + ((c ^ (row & 7)) << 3)];
                    oacc[db] = __builtin_amdgcn_mfma_f32_32x32x16_bf16(paf, vf, oacc[db], 0, 0, 0);
                }
            }
            __builtin_amdgcn_s_setprio(0);
        }
        __syncthreads();
    };

    for (int kt = 0; kt < 32; kt += 2) {
        iter(kt,     K0, V0, K1, V1);
        iter(kt + 1, K1, V1, K0, V0);
    }

    float lsum = lacc + __shfl_xor(lacc, 32);
    if (l < 32) ltab[w][l] = lsum;
    asm volatile("s_waitcnt lgkmcnt(0)" ::: "memory");

    float linv[16];
#pragma unroll
    for (int r = 0; r < 16; ++r) {
        const int q = (r & 3) + 8 * (r >> 2) + 4 * hi;
        linv[r] = 1.0f / ltab[w][q];
    }

    const int b = bh >> 3, h2 = bh & 7;
    const size_t rowbase = (size_t)b * 2048 + qt * 128 + w * 32;
#pragma unroll
    for (int db = 0; db < 3; ++db) {
#pragma unroll
        for (int r = 0; r < 16; ++r) {
            const int q = (r & 3) + 8 * (r >> 2) + 4 * hi;
            AO[(rowbase + q) * 768 + h2 * 96 + db * 32 + ql] = f2bf(oacc[db][r] * linv[r]);
        }
    }
}

// ---------------- GEMM2: AO[16384][768] @ WprojT[768][768]^T + b -> out f32 (2-phase) ----
__global__ __launch_bounds__(256, 2) void gemm2_kernel(
    const short* __restrict__ A, const short* __restrict__ BT,
    const float* __restrict__ bias, float* __restrict__ out)
{
    __shared__ short As[2][128][64];
    __shared__ short Bs[2][128][64];
    const int K = 768;
    const int t = threadIdx.x;
    const int w = t >> 6, l = t & 63;
    const int wr = w >> 1, wc = w & 1;
    const int lr = l & 15, lg = l >> 4;

    const int srow = w * 32 + (l >> 3);
    const int scol = (l & 7) * 8;
    const short* Ag = A + (size_t)blockIdx.x * 128 * K + (size_t)srow * K + scol;
    const short* Bg = BT + (size_t)blockIdx.y * 128 * K + (size_t)srow * K + scol;

    const f32x4 z4 = {0.f, 0.f, 0.f, 0.f};
    f32x4 acc[4][4];
#pragma unroll
    for (int i = 0; i < 4; ++i)
#pragma unroll
        for (int j = 0; j < 4; ++j) acc[i][j] = z4;

    auto stage = [&](int kt, int buf) {
#pragma unroll
        for (int i = 0; i < 4; ++i) {
            gload_lds16(Ag + kt * 64 + (size_t)(i * 8) * K, &As[buf][w * 32 + i * 8][0]);
            gload_lds16(Bg + kt * 64 + (size_t)(i * 8) * K, &Bs[buf][w * 32 + i * 8][0]);
        }
    };
    auto compute = [&](int buf) {
#pragma unroll
        for (int kk = 0; kk < 2; ++kk) {
            bf16x8 af[4], bfr[4];
#pragma unroll
            for (int mi = 0; mi < 4; ++mi)
                af[mi] = *(const bf16x8*)&As[buf][wr * 64 + mi * 16 + lr][kk * 32 + lg * 8];
#pragma unroll
            for (int ni = 0; ni < 4; ++ni)
                bfr[ni] = *(const bf16x8*)&Bs[buf][wc * 64 + ni * 16 + lr][kk * 32 + lg * 8];
#pragma unroll
            for (int mi = 0; mi < 4; ++mi)
#pragma unroll
                for (int ni = 0; ni < 4; ++ni)
                    acc[mi][ni] = __builtin_amdgcn_mfma_f32_16x16x32_bf16(
                        af[mi], bfr[ni], acc[mi][ni], 0, 0, 0);
        }
    };

    stage(0, 0);
    __syncthreads();
    for (int kt = 0; kt < 12; kt += 2) {
        stage(kt + 1, 1);
        compute(0);
        __syncthreads();
        if (kt + 2 < 12) stage(kt + 2, 0);
        compute(1);
        __syncthreads();
    }

    const int rb = blockIdx.x * 128 + wr * 64;
    const int cb = blockIdx.y * 128 + wc * 64;
#pragma unroll
    for (int ni = 0; ni < 4; ++ni) {
        const int c = cb + ni * 16 + lr;
        const float bv = bias[c];
#pragma unroll
        for (int mi = 0; mi < 4; ++mi) {
            const int r0 = rb + mi * 16 + lg * 4;
#pragma unroll
            for (int r = 0; r < 4; ++r)
                out[(size_t)(r0 + r) * 768 + c] = acc[mi][ni][r] + bv;
        }
    }
}

extern "C" void kernel_launch(void* const* d_in, const int* in_sizes, int n_in,
                              void* d_out, int out_size, void* d_ws, size_t ws_size,
                              hipStream_t stream) {
    const float* x     = (const float*)d_in[0];
    const float* Wqkv  = (const float*)d_in[1];
    const float* bqkv  = (const float*)d_in[2];
    const float* Wproj = (const float*)d_in[3];
    const float* bproj = (const float*)d_in[4];
    float* out = (float*)d_out;

    char* ws = (char*)d_ws;
    short* xb     = (short*)(ws);                 // 25,165,824 B (aliased as AO later)
    short* WqkvT  = (short*)(ws + 25165824);      //  3,538,944 B
    short* WprojT = (short*)(ws + 28704768);      //  1,179,648 B
    short* Qh     = (short*)(ws + 29884416);      // 25,165,824 B  [64][2048][96]
    short* Kh     = (short*)(ws + 55050240);      // 27,262,976 B  [64][2048][104]
    short* Vt     = (short*)(ws + 82313216);      // 25,165,824 B  [64][32][96][64] swizzled
    short* AO     = xb;  // xb is dead after gemm1; reuse for attention output

    cast_kernel<<<12288, 256, 0, stream>>>(x, xb, 3145728);
    transpose_cast_kernel<<<dim3(36, 12), 256, 0, stream>>>(Wqkv, WqkvT, 768, 2304);
    transpose_cast_kernel<<<dim3(12, 12), 256, 0, stream>>>(Wproj, WprojT, 768, 768);
    gemm1_kernel<<<dim3(128, 18), 256, 0, stream>>>(xb, WqkvT, bqkv, Qh, Kh, Vt);
    attn_kernel<<<dim3(16, 64), 256, 0, stream>>>(Qh, Kh, Vt, AO);
    gemm2_kernel<<<dim3(128, 6), 256, 0, stream>>>(AO, WprojT, bproj, out);
}

// Round 8
// 236.016 us; speedup vs baseline: 1.1829x; 1.1829x over previous
//
#include <hip/hip_runtime.h>
#include <hip/hip_bf16.h>

typedef __attribute__((ext_vector_type(8))) short bf16x8;
typedef __attribute__((ext_vector_type(4))) short bf16x4;
typedef __attribute__((ext_vector_type(4))) float f32x4;
typedef __attribute__((ext_vector_type(16))) float f32x16;
typedef __attribute__((ext_vector_type(4))) unsigned int uint4v;

__device__ __forceinline__ short f2bf(float f) {
    unsigned int u = __float_as_uint(f);
    u += 0x7FFFu + ((u >> 16) & 1u);   // round-to-nearest-even
    return (short)(u >> 16);
}

__device__ __forceinline__ unsigned cvtpk(float lo, float hi) {
    unsigned r;
    asm("v_cvt_pk_bf16_f32 %0, %1, %2" : "=v"(r) : "v"(lo), "v"(hi));
    return r;
}

// async global -> LDS, 16 B per lane; LDS dest = wave-uniform base + lane*16
__device__ __forceinline__ void gload_lds16(const void* g, void* l) {
    __builtin_amdgcn_global_load_lds(
        (const __attribute__((address_space(1))) void*)g,
        (__attribute__((address_space(3))) void*)l, 16, 0, 0);
}

// ---------------- prep: blocks [0,2048) cast x->bf16 (grid-stride, 6 iters);
//                  [2048,2480) Wqkv transpose; [2480,2624) Wproj transpose ----------------
__global__ __launch_bounds__(256) void prep_kernel(
    const float* __restrict__ x, short* __restrict__ xb,
    const float* __restrict__ Wqkv, short* __restrict__ WqkvT,
    const float* __restrict__ Wproj, short* __restrict__ WprojT)
{
    __shared__ float tile[64][65];
    const int t = threadIdx.x;
    const unsigned bx = blockIdx.x;
    if (bx < 2048) {
        // cast: 3,145,728 f32x4 quads; 524,288 threads x 6 iters
        size_t base = (size_t)bx * 256 + t;
#pragma unroll
        for (int it = 0; it < 6; ++it) {
            size_t i = base + (size_t)it * 524288;
            const f32x4 v = *(const f32x4*)(x + i * 4);
            bf16x4 o;
            o[0] = f2bf(v[0]); o[1] = f2bf(v[1]); o[2] = f2bf(v[2]); o[3] = f2bf(v[3]);
            *(bf16x4*)(xb + i * 4) = o;
        }
        return;
    }
    const float* W; short* WT; int C, tiles_x, tt;
    if (bx < 2480) { W = Wqkv;  WT = WqkvT;  C = 2304; tiles_x = 36; tt = (int)bx - 2048; }
    else           { W = Wproj; WT = WprojT; C = 768;  tiles_x = 12; tt = (int)bx - 2480; }
    const int R = 768;
    const int bc = (tt % tiles_x) * 64;
    const int br = (tt / tiles_x) * 64;
#pragma unroll
    for (int i = 0; i < 16; ++i) {
        int o = t + 256 * i;
        int r = o >> 6, c = o & 63;
        tile[r][c] = W[(size_t)(br + r) * C + bc + c];
    }
    __syncthreads();
#pragma unroll
    for (int i = 0; i < 16; ++i) {
        int o = t + 256 * i;
        int c = o >> 6, r = o & 63;
        WT[(size_t)(bc + c) * R + br + r] = f2bf(tile[r][c]);
    }
}

// ---------------- GEMM1: xb[16384][768] @ WqkvT[2304][768]^T + b ->
//     Qh (pre-scaled by 1/sqrt(768)*log2(e)), Kh, Vt (bf16)
//     m97-style: global_load_lds width-16 staging into LINEAR [128][64] LDS ----------------
__global__ __launch_bounds__(256, 4) void gemm1_kernel(
    const short* __restrict__ A, const short* __restrict__ BT,
    const float* __restrict__ bias,
    short* __restrict__ Qh, short* __restrict__ Kh, short* __restrict__ Vt)
{
    __shared__ short As[128][64];
    __shared__ short Bs[128][64];
    const int K = 768;
    const int t = threadIdx.x;
    const int w = t >> 6, l = t & 63;
    const int wr = w >> 1, wc = w & 1;
    const int lr = l & 15, lg = l >> 4;

    // staging geometry: lane l covers row (l>>3), 16 B chunk (l&7) of a 8-row group
    const int srow = w * 32 + (l >> 3);
    const int scol = (l & 7) * 8;
    const short* Ag = A + (size_t)blockIdx.x * 128 * K + (size_t)srow * K + scol;
    const short* Bg = BT + (size_t)blockIdx.y * 128 * K + (size_t)srow * K + scol;

    const f32x4 z4 = {0.f, 0.f, 0.f, 0.f};
    f32x4 acc[4][4];
#pragma unroll
    for (int i = 0; i < 4; ++i)
#pragma unroll
        for (int j = 0; j < 4; ++j) acc[i][j] = z4;

    for (int kt = 0; kt < K; kt += 64) {
#pragma unroll
        for (int i = 0; i < 4; ++i) {
            gload_lds16(Ag + kt + (size_t)(i * 8) * K, &As[w * 32 + i * 8][0]);
            gload_lds16(Bg + kt + (size_t)(i * 8) * K, &Bs[w * 32 + i * 8][0]);
        }
        __syncthreads();   // drains vmcnt (global_load_lds) + lgkm
#pragma unroll
        for (int kk = 0; kk < 2; ++kk) {
            bf16x8 af[4], bfr[4];
#pragma unroll
            for (int mi = 0; mi < 4; ++mi)
                af[mi] = *(const bf16x8*)&As[wr * 64 + mi * 16 + lr][kk * 32 + lg * 8];
#pragma unroll
            for (int ni = 0; ni < 4; ++ni)
                bfr[ni] = *(const bf16x8*)&Bs[wc * 64 + ni * 16 + lr][kk * 32 + lg * 8];
#pragma unroll
            for (int mi = 0; mi < 4; ++mi)
#pragma unroll
                for (int ni = 0; ni < 4; ++ni)
                    acc[mi][ni] = __builtin_amdgcn_mfma_f32_16x16x32_bf16(
                        af[mi], bfr[ni], acc[mi][ni], 0, 0, 0);
        }
        __syncthreads();
    }

    const float qs = 0.05205877f; // (1/sqrt(768)) * log2(e), folded into Q
    const int rb = blockIdx.x * 128 + wr * 64;
    const int cb = blockIdx.y * 128 + wc * 64;
#pragma unroll
    for (int ni = 0; ni < 4; ++ni) {
        const int c = cb + ni * 16 + lr;
        const float bv = bias[c];
        const int which = (c >= 1536) ? 2 : (c >= 768 ? 1 : 0);
        const int cc = c - which * 768;
        const int h = cc / 96;
        const int d = cc - h * 96;
#pragma unroll
        for (int mi = 0; mi < 4; ++mi) {
            const int r0 = rb + mi * 16 + lg * 4;
            const int b = r0 >> 11, n0 = r0 & 2047;
            const int hb = b * 8 + h;
            if (which == 2) {
                bf16x4 pk;
#pragma unroll
                for (int r = 0; r < 4; ++r) pk[r] = f2bf(acc[mi][ni][r] + bv);
                *(bf16x4*)&Vt[((size_t)hb * 96 + d) * 2048 + n0] = pk;
            } else if (which == 1) {
#pragma unroll
                for (int r = 0; r < 4; ++r)
                    Kh[((size_t)hb * 2048 + n0 + r) * 96 + d] = f2bf(acc[mi][ni][r] + bv);
            } else {
#pragma unroll
                for (int r = 0; r < 4; ++r)
                    Qh[((size_t)hb * 2048 + n0 + r) * 96 + d] = f2bf((acc[mi][ni][r] + bv) * qs);
            }
        }
    }
}

// ---------------- attention: QBLK=128 (4 waves x 32 q-rows), KVBLK=64, 32x32x16 MFMA,
//   double-buffered K/V LDS (1 barrier/iter), in-register P, ltab aliased. (R5 best) ----
__global__ __launch_bounds__(256, 2) void attn_kernel(
    const short* __restrict__ Qh, const short* __restrict__ Kh,
    const short* __restrict__ Vt, short* __restrict__ AO)
{
    // Ks0|Ks1: 64x104 each (13312 B); Vs0|Vs1: 96x72 each (13824 B). Qs aliases Ks0+Ks1.
    // ltab (4x32 f32 = 512 B) aliases smem base (dead K/V region) after the K-loop.
    __shared__ __align__(16) char smem[54272];
    short (*Ks0)[104] = (short (*)[104])smem;
    short (*Ks1)[104] = (short (*)[104])(smem + 13312);
    short (*Vs0)[72]  = (short (*)[72])(smem + 26624);
    short (*Vs1)[72]  = (short (*)[72])(smem + 40448);
    short (*Qs)[104]  = (short (*)[104])smem;   // 128x104x2 = 26624 B
    float (*ltab)[32] = (float (*)[32])smem;

    const int t = threadIdx.x;
    const int w = t >> 6, l = t & 63;
    const int ql = l & 31, hi = l >> 5;

    // XCD-aware swizzle: each XCD walks the 16 q-tiles of one head consecutively
    const unsigned L = blockIdx.y * 16 + blockIdx.x;       // linear dispatch id
    const int bh = (int)((L & 7) + 8 * (L >> 7));
    const int qt = (int)((L >> 3) & 15);

    const short* Qg = Qh + (size_t)bh * 2048 * 96 + (size_t)qt * 128 * 96;
    const short* Kg = Kh + (size_t)bh * 2048 * 96;
    const short* Vg = Vt + (size_t)bh * 96 * 2048;

    // prologue global loads for kt=0 (issued first; land under Q staging)
    bf16x8 kreg[3], vreg[3];
#pragma unroll
    for (int i = 0; i < 3; ++i) {
        int o = t + 256 * i;
        kreg[i] = *(const bf16x8*)(Kg + 8 * (size_t)o);
        vreg[i] = *(const bf16x8*)(Vg + (size_t)(o >> 3) * 2048 + (o & 7) * 8);
    }

    // stage Q (128x96) -> LDS, then pull per-wave Q B-frags into registers
#pragma unroll
    for (int i = 0; i < 6; ++i) {
        int o = t + 256 * i;
        *(bf16x8*)&Qs[o / 12][(o % 12) * 8] = *(const bf16x8*)(Qg + 8 * (size_t)o);
    }
    __syncthreads();
    bf16x8 qf[6];
#pragma unroll
    for (int kk = 0; kk < 6; ++kk)
        qf[kk] = *(const bf16x8*)&Qs[w * 32 + ql][kk * 16 + hi * 8];
    __syncthreads();   // Qs dead; Ks0/Ks1 may be overwritten

    // write kt=0 tile, load kt=1
#pragma unroll
    for (int i = 0; i < 3; ++i) {
        int o = t + 256 * i;
        *(bf16x8*)&Ks0[o / 12][(o % 12) * 8] = kreg[i];
        *(bf16x8*)&Vs0[o >> 3][(o & 7) * 8] = vreg[i];
    }
#pragma unroll
    for (int i = 0; i < 3; ++i) {
        int o = t + 256 * i;
        kreg[i] = *(const bf16x8*)(Kg + (size_t)64 * 96 + 8 * (size_t)o);
        vreg[i] = *(const bf16x8*)(Vg + (size_t)(o >> 3) * 2048 + 64 + (o & 7) * 8);
    }
    __syncthreads();   // buf0 ready

    f32x16 oacc[3];
#pragma unroll
    for (int i = 0; i < 3; ++i)
#pragma unroll
        for (int r = 0; r < 16; ++r) oacc[i][r] = 0.f;
    float lacc = 0.f;

    auto iter = [&](int kt, short (*rK)[104], short (*rV)[72],
                    short (*wK)[104], short (*wV)[72]) {
        // write tile kt+1 into the other buffer (prev-iter barrier protects it)
        if (kt < 31) {
#pragma unroll
            for (int i = 0; i < 3; ++i) {
                int o = t + 256 * i;
                *(bf16x8*)&wK[o / 12][(o % 12) * 8] = kreg[i];
                *(bf16x8*)&wV[o >> 3][(o & 7) * 8] = vreg[i];
            }
        }
        // issue global loads for tile kt+2 (hide latency under this iter's compute)
        if (kt < 30) {
            const size_t koff = (size_t)(kt + 2) * 64 * 96;
            const int moff = (kt + 2) * 64;
#pragma unroll
            for (int i = 0; i < 3; ++i) {
                int o = t + 256 * i;
                kreg[i] = *(const bf16x8*)(Kg + koff + 8 * (size_t)o);
                vreg[i] = *(const bf16x8*)(Vg + (size_t)(o >> 3) * 2048 + moff + (o & 7) * 8);
            }
        }

        // ---- S^T = K @ Q^T ----
        f32x16 sa0, sa1;
#pragma unroll
        for (int r = 0; r < 16; ++r) { sa0[r] = 0.f; sa1[r] = 0.f; }
        __builtin_amdgcn_s_setprio(1);
#pragma unroll
        for (int kk = 0; kk < 6; ++kk) {
            bf16x8 kf0 = *(const bf16x8*)&rK[ql][kk * 16 + hi * 8];
            bf16x8 kf1 = *(const bf16x8*)&rK[32 + ql][kk * 16 + hi * 8];
            sa0 = __builtin_amdgcn_mfma_f32_32x32x16_bf16(kf0, qf[kk], sa0, 0, 0, 0);
            sa1 = __builtin_amdgcn_mfma_f32_32x32x16_bf16(kf1, qf[kk], sa1, 0, 0, 0);
        }
        __builtin_amdgcn_s_setprio(0);

        // ---- softmax numerator (exp2; scale pre-folded into Q) + repack ----
        bf16x8 pa[4];
#pragma unroll
        for (int mi = 0; mi < 2; ++mi) {
            float p[16];
#pragma unroll
            for (int r = 0; r < 16; ++r) {
                p[r] = __builtin_amdgcn_exp2f(mi == 0 ? sa0[r] : sa1[r]);
                lacc += p[r];
            }
            unsigned x0 = cvtpk(p[0], p[1]),  y0 = cvtpk(p[4], p[5]);
            unsigned x1 = cvtpk(p[2], p[3]),  y1 = cvtpk(p[6], p[7]);
            unsigned x2 = cvtpk(p[8], p[9]),  y2 = cvtpk(p[12], p[13]);
            unsigned x3 = cvtpk(p[10], p[11]), y3 = cvtpk(p[14], p[15]);
            asm("v_permlane32_swap_b32 %0, %1" : "+v"(x0), "+v"(y0));
            asm("v_permlane32_swap_b32 %0, %1" : "+v"(x1), "+v"(y1));
            asm("v_permlane32_swap_b32 %0, %1" : "+v"(x2), "+v"(y2));
            asm("v_permlane32_swap_b32 %0, %1" : "+v"(x3), "+v"(y3));
            uint4v uA; uA[0] = x0; uA[1] = x1; uA[2] = y0; uA[3] = y1;
            uint4v uB; uB[0] = x2; uB[1] = x3; uB[2] = y2; uB[3] = y3;
            pa[mi * 2 + 0] = __builtin_bit_cast(bf16x8, uA);
            pa[mi * 2 + 1] = __builtin_bit_cast(bf16x8, uB);
        }

        // ---- O += P @ V ----
        __builtin_amdgcn_s_setprio(1);
#pragma unroll
        for (int kb = 0; kb < 4; ++kb) {
#pragma unroll
            for (int db = 0; db < 3; ++db) {
                bf16x8 vf = *(const bf16x8*)&rV[db * 32 + ql][kb * 16 + hi * 8];
                oacc[db] = __builtin_amdgcn_mfma_f32_32x32x16_bf16(pa[kb], vf, oacc[db], 0, 0, 0);
            }
        }
        __builtin_amdgcn_s_setprio(0);
        __syncthreads();
    };

    for (int kt = 0; kt < 32; kt += 2) {
        iter(kt,     Ks0, Vs0, Ks1, Vs1);
        iter(kt + 1, Ks1, Vs1, Ks0, Vs0);
    }

    // ---- softmax denominator (ltab aliases dead K/V LDS; intra-wave only) ----
    float lsum = lacc + __shfl_xor(lacc, 32);
    if (l < 32) ltab[w][l] = lsum;
    asm volatile("s_waitcnt lgkmcnt(0)" ::: "memory");

    float linv[16];
#pragma unroll
    for (int r = 0; r < 16; ++r) {
        const int q = (r & 3) + 8 * (r >> 2) + 4 * hi;
        linv[r] = 1.0f / ltab[w][q];
    }

    const int b = bh >> 3, h = bh & 7;
    const size_t rowbase = (size_t)b * 2048 + qt * 128 + w * 32;
#pragma unroll
    for (int db = 0; db < 3; ++db) {
#pragma unroll
        for (int r = 0; r < 16; ++r) {
            const int q = (r & 3) + 8 * (r >> 2) + 4 * hi;
            AO[(rowbase + q) * 768 + h * 96 + db * 32 + ql] = f2bf(oacc[db][r] * linv[r]);
        }
    }
}

// ---------------- GEMM2: AO[16384][768] @ WprojT[768][768]^T + b -> out f32 ----------------
__global__ __launch_bounds__(256, 4) void gemm2_kernel(
    const short* __restrict__ A, const short* __restrict__ BT,
    const float* __restrict__ bias, float* __restrict__ out)
{
    __shared__ short As[128][64];
    __shared__ short Bs[128][64];
    const int K = 768;
    const int t = threadIdx.x;
    const int w = t >> 6, l = t & 63;
    const int wr = w >> 1, wc = w & 1;
    const int lr = l & 15, lg = l >> 4;

    const int srow = w * 32 + (l >> 3);
    const int scol = (l & 7) * 8;
    const short* Ag = A + (size_t)blockIdx.x * 128 * K + (size_t)srow * K + scol;
    const short* Bg = BT + (size_t)blockIdx.y * 128 * K + (size_t)srow * K + scol;

    const f32x4 z4 = {0.f, 0.f, 0.f, 0.f};
    f32x4 acc[4][4];
#pragma unroll
    for (int i = 0; i < 4; ++i)
#pragma unroll
        for (int j = 0; j < 4; ++j) acc[i][j] = z4;

    for (int kt = 0; kt < K; kt += 64) {
#pragma unroll
        for (int i = 0; i < 4; ++i) {
            gload_lds16(Ag + kt + (size_t)(i * 8) * K, &As[w * 32 + i * 8][0]);
            gload_lds16(Bg + kt + (size_t)(i * 8) * K, &Bs[w * 32 + i * 8][0]);
        }
        __syncthreads();
#pragma unroll
        for (int kk = 0; kk < 2; ++kk) {
            bf16x8 af[4], bfr[4];
#pragma unroll
            for (int mi = 0; mi < 4; ++mi)
                af[mi] = *(const bf16x8*)&As[wr * 64 + mi * 16 + lr][kk * 32 + lg * 8];
#pragma unroll
            for (int ni = 0; ni < 4; ++ni)
                bfr[ni] = *(const bf16x8*)&Bs[wc * 64 + ni * 16 + lr][kk * 32 + lg * 8];
#pragma unroll
            for (int mi = 0; mi < 4; ++mi)
#pragma unroll
                for (int ni = 0; ni < 4; ++ni)
                    acc[mi][ni] = __builtin_amdgcn_mfma_f32_16x16x32_bf16(
                        af[mi], bfr[ni], acc[mi][ni], 0, 0, 0);
        }
        __syncthreads();
    }

    const int rb = blockIdx.x * 128 + wr * 64;
    const int cb = blockIdx.y * 128 + wc * 64;
#pragma unroll
    for (int ni = 0; ni < 4; ++ni) {
        const int c = cb + ni * 16 + lr;
        const float bv = bias[c];
#pragma unroll
        for (int mi = 0; mi < 4; ++mi) {
            const int r0 = rb + mi * 16 + lg * 4;
#pragma unroll
            for (int r = 0; r < 4; ++r)
                out[(size_t)(r0 + r) * 768 + c] = acc[mi][ni][r] + bv;
        }
    }
}

extern "C" void kernel_launch(void* const* d_in, const int* in_sizes, int n_in,
                              void* d_out, int out_size, void* d_ws, size_t ws_size,
                              hipStream_t stream) {
    const float* x     = (const float*)d_in[0];
    const float* Wqkv  = (const float*)d_in[1];
    const float* bqkv  = (const float*)d_in[2];
    const float* Wproj = (const float*)d_in[3];
    const float* bproj = (const float*)d_in[4];
    float* out = (float*)d_out;

    char* ws = (char*)d_ws;
    short* xb     = (short*)(ws);                 // 25,165,824 B (aliased as AO later)
    short* WqkvT  = (short*)(ws + 25165824);      //  3,538,944 B
    short* WprojT = (short*)(ws + 28704768);      //  1,179,648 B
    short* Qh     = (short*)(ws + 29884416);      // 25,165,824 B  [64][2048][96]
    short* Kh     = (short*)(ws + 55050240);      // 25,165,824 B  [64][2048][96]
    short* Vt     = (short*)(ws + 80216064);      // 25,165,824 B  [64][96][2048]
    short* AO     = xb;  // xb is dead after gemm1; reuse for attention output

    prep_kernel<<<2624, 256, 0, stream>>>(x, xb, Wqkv, WqkvT, Wproj, WprojT);
    gemm1_kernel<<<dim3(128, 18), 256, 0, stream>>>(xb, WqkvT, bqkv, Qh, Kh, Vt);
    attn_kernel<<<dim3(16, 64), 256, 0, stream>>>(Qh, Kh, Vt, AO);
    gemm2_kernel<<<dim3(128, 6), 256, 0, stream>>>(AO, WprojT, bproj, out);
}